// Round 5
// baseline (144.897 us; speedup 1.0000x reference)
//
#include <hip/hip_runtime.h>
#include <hip/hip_bf16.h>

// out[64,8192] = x[64,8192] @ dequant(w2bit)[8192,8192]^T + bias
#define B_    64
#define IN_   8192
#define OUT_  8192
#define NG_   128      // quant groups per row (IN/64)
#define PB_   2048     // packed bytes per weight row (IN/4)
#define KSPLIT 16
#define KC    512      // k per block

typedef float f32x4 __attribute__((ext_vector_type(4)));
typedef short s16x8 __attribute__((ext_vector_type(8)));
typedef _Float16 f16x4 __attribute__((ext_vector_type(4)));

// ws layout (bytes):
//   xfrag : 0        .. 1 MB    (x in per-kidx fragment-slot order, bf16)
//   wq    : 1 MB     .. 17 MB   (weights transposed to [kidx][row][128B])
//   tab   : 17 MB    .. 25 MB   (dequant LUT, uint4 per (kidx,n,q))
//   part  : 25 MB    .. 41 MB   (16 fp16 partial planes)
//   flag  : 41 MB
#define OFF_WQ   (1u << 20)
#define OFF_TAB  (17u << 20)
#define OFF_PART (25u << 20)
#define OFF_FLAG (41u << 20)

// ---- detect weight dtype: u8 packed (words >255 appear) vs int32-widened ----
__global__ __launch_bounds__(256) void k_flag(const unsigned* __restrict__ wp,
                                              int* __restrict__ flag) {
    __shared__ int f;
    unsigned any = 0;
#pragma unroll
    for (int i = 0; i < 16; ++i)
        any |= (wp[i * 256 + threadIdx.x] > 255u) ? 1u : 0u;
    if (threadIdx.x == 0) f = 0;
    __syncthreads();
    if (any) f = 1;
    __syncthreads();
    if (threadIdx.x == 0) *flag = f;   // 1 = raw uint8, 0 = int32-widened
}

// ---- weight transpose: wp[row][16 x 128B] -> wq[kidx][row][128B] ----
// Block: 16 rows x 16 chunks; thread (c=tid>>4, rl=tid&15) moves one 128 B run.
__global__ __launch_bounds__(256) void k_wpack(const unsigned char* __restrict__ wp,
                                               unsigned char* __restrict__ wq,
                                               const int* __restrict__ flag) {
    const int c  = threadIdx.x >> 4;          // chunk = kidx
    const int r  = blockIdx.x * 16 + (threadIdx.x & 15);
    uint4 v[8];
    if (*flag) {
        const uint4* src = (const uint4*)(wp + r * PB_ + c * 128);
#pragma unroll
        for (int u = 0; u < 8; ++u) v[u] = src[u];
    } else {  // cold path: one byte per int32 element
        const int* src = (const int*)wp + r * PB_ + c * 128;
#pragma unroll
        for (int u = 0; u < 8; ++u) {
            unsigned d[4];
#pragma unroll
            for (int w = 0; w < 4; ++w) {
                const int* p = src + u * 16 + w * 4;
                d[w] = (unsigned)(p[0] & 0xFF) | ((unsigned)(p[1] & 0xFF) << 8) |
                       ((unsigned)(p[2] & 0xFF) << 16) | ((unsigned)(p[3] & 0xFF) << 24);
            }
            v[u] = (uint4){d[0], d[1], d[2], d[3]};
        }
    }
    uint4* dst = (uint4*)(wq + ((unsigned)c * OUT_ + r) * 128);
#pragma unroll
    for (int u = 0; u < 8; ++u) dst[u] = v[u];
}

// ---- dequant LUT: tab[kidx][n][g&7] = 4 bf16 {(c-zp)*s, c=0..3} (8 B) ----
__global__ __launch_bounds__(256) void k_spack(const float* __restrict__ scales,
                                               const int* __restrict__ zps,
                                               uint2* __restrict__ tab) {
    const int e = blockIdx.x * 256 + threadIdx.x;   // == n*128 + g
    const int n = e >> 7, g = e & 127;
    const float s = scales[e];
    const float zf = (float)zps[e];
    const float v0 = -zf * s, v1 = v0 + s, v2 = v1 + s, v3 = v2 + s;
    __hip_bfloat162 lo = __float22bfloat162_rn(make_float2(v0, v1));
    __hip_bfloat162 hi = __float22bfloat162_rn(make_float2(v2, v3));
    uint2 ent; ent.x = *(unsigned*)&lo; ent.y = *(unsigned*)&hi;
    tab[(((unsigned)(g >> 3) * OUT_) + n) * 8 + (g & 7)] = ent;
}

// ---- x: fp32 -> bf16 in per-kidx MFMA fragment-slot order ----
// slot idx = sg*64 + lane; sg = (sb*4+b)*4 + mt; lane=(q,nn):
//   xfrag[kidx][idx] <- x[mt*16+nn][kidx*512 + q*128 + sb*32 + b*8 .. +8)
__global__ __launch_bounds__(256) void k_pre(const float* __restrict__ x,
                                             uint4* __restrict__ xfrag) {
    const int kidx = blockIdx.x >> 2;
    const int part = blockIdx.x & 3;
#pragma unroll
    for (int i = 0; i < 4; ++i) {
        const int idx = (part * 4 + i) * 256 + threadIdx.x;   // 0..4095
        const int sg = idx >> 6, lane = idx & 63;
        const int tt = sg >> 2, mt = sg & 3;
        const int sb = tt >> 2, b = tt & 3;
        const int q = lane >> 4, nn = lane & 15;
        const float* src = x + (mt * 16 + nn) * IN_ + kidx * KC + q * 128 + sb * 32 + b * 8;
        const float4 f0 = *(const float4*)src;
        const float4 f1 = *(const float4*)(src + 4);
        __hip_bfloat162 h0 = __float22bfloat162_rn(make_float2(f0.x, f0.y));
        __hip_bfloat162 h1 = __float22bfloat162_rn(make_float2(f0.z, f0.w));
        __hip_bfloat162 h2 = __float22bfloat162_rn(make_float2(f1.x, f1.y));
        __hip_bfloat162 h3 = __float22bfloat162_rn(make_float2(f1.z, f1.w));
        uint4 o;
        o.x = *(unsigned*)&h0; o.y = *(unsigned*)&h1;
        o.z = *(unsigned*)&h2; o.w = *(unsigned*)&h3;
        xfrag[kidx * 4096 + idx] = o;
    }
}

// ---- main: 32 col-blocks(256) x 16 k-splits; 256 thr = 4 waves x 64 cols ----
// All global reads are contiguous streams now (wq / tab / xfrag).
__global__ __launch_bounds__(256, 2) void k_main(
    const uint4* __restrict__ xfrag,
    const unsigned char* __restrict__ wq,
    const uint4* __restrict__ tab,
    _Float16* __restrict__ part)
{
    __shared__ uint4 x_lds[4096];   // 64 KB

    const int tid  = threadIdx.x;
    const int wave = tid >> 6;
    const int lane = tid & 63;
    const int q    = lane >> 4;
    const int nn   = lane & 15;

    const int kidx    = blockIdx.x & (KSPLIT - 1);
    const int nblk    = blockIdx.x >> 4;
    const int colbase = nblk * 256 + wave * 64;

    // weight loads: contiguous 32 KB block region, fully lane-coalesced
    uint4 w4[4][2];
#pragma unroll
    for (int cg = 0; cg < 4; ++cg) {
        const unsigned n = colbase + cg * 16 + nn;
        const uint4* src = (const uint4*)(wq + ((unsigned)kidx * OUT_ + n) * 128 + q * 32);
        w4[cg][0] = src[0];
        w4[cg][1] = src[1];
    }
    // LUT loads: one dwordx4 per cg = {L(sp0),H(sp0),L(sp1),H(sp1)}
    uint4 tq[4];
#pragma unroll
    for (int cg = 0; cg < 4; ++cg) {
        const unsigned n = colbase + cg * 16 + nn;
        tq[cg] = tab[((unsigned)kidx * OUT_ + n) * 4 + q];
    }
    // async stage x chunk -> LDS (contiguous 1 KB per DMA)
#pragma unroll
    for (int i = 0; i < 16; ++i) {
        const int sg = wave * 16 + i;
        const uint4* src = xfrag + kidx * 4096 + sg * 64 + lane;
        __builtin_amdgcn_global_load_lds(
            (const __attribute__((address_space(1))) unsigned int*)src,
            (__attribute__((address_space(3))) unsigned int*)
                ((char*)x_lds + sg * 1024),
            16, 0, 0);
    }
    __syncthreads();   // drains DMA + register loads

    f32x4 acc[4][4];
#pragma unroll
    for (int cg = 0; cg < 4; ++cg)
#pragma unroll
        for (int mt = 0; mt < 4; ++mt)
            acc[cg][mt] = (f32x4){0.f, 0.f, 0.f, 0.f};

    // pure-compute body: 16 ksteps x 16 MFMA
#pragma unroll
    for (int sb = 0; sb < 4; ++sb) {
#pragma unroll
        for (int b = 0; b < 4; ++b) {
            const int t = sb * 4 + b;
            union { uint4 u4; s16x8 s8; } av[4];
#pragma unroll
            for (int mt = 0; mt < 4; ++mt)
                av[mt].u4 = x_lds[(t * 4 + mt) * 64 + lane];
#pragma unroll
            for (int cg = 0; cg < 4; ++cg) {
                const uint4 ch = w4[cg][sb >> 1];
                const unsigned dwv =
                    ((const unsigned*)&ch)[((sb & 1) << 1) | (b >> 1)];
                const unsigned u = (b & 1) ? (dwv >> 16) : (dwv & 0xFFFFu);
                const unsigned tl = (sb >> 1) ? tq[cg].z : tq[cg].x;
                const unsigned th = (sb >> 1) ? tq[cg].w : tq[cg].y;
                union { unsigned w[4]; s16x8 s8; } bf;
#pragma unroll
                for (int m = 0; m < 4; ++m) {
                    const unsigned c0 = (u >> (4 * m)) & 3u;
                    const unsigned c1 = (u >> (4 * m + 2)) & 3u;
                    const unsigned sel = (0x0100u + c0 * 0x0202u)
                                       | ((0x0100u + c1 * 0x0202u) << 16);
                    bf.w[m] = __builtin_amdgcn_perm(th, tl, sel);
                }
#pragma unroll
                for (int mt = 0; mt < 4; ++mt)
                    acc[cg][mt] = __builtin_amdgcn_mfma_f32_16x16x32_bf16(
                        av[mt].s8, bf.s8, acc[cg][mt], 0, 0, 0);
            }
        }
    }

    // epilogue: fp16 partial plane [b][n]; one wave covers a full 128 B line
    _Float16* pp = part + kidx * (B_ * OUT_);
#pragma unroll
    for (int cg = 0; cg < 4; ++cg) {
        const int col = colbase + cg * 16 + nn;
#pragma unroll
        for (int mt = 0; mt < 4; ++mt)
#pragma unroll
            for (int r = 0; r < 4; ++r)
                pp[(mt * 16 + q * 4 + r) * OUT_ + col] = (_Float16)acc[cg][mt][r];
    }
}

// out = bias + sum of 16 fp16 partial planes (pure coalesced stream)
__global__ __launch_bounds__(256) void k_reduce(const _Float16* __restrict__ part,
                                                const float* __restrict__ bias,
                                                float* __restrict__ out) {
    const int gtid = blockIdx.x * 256 + threadIdx.x;
    const int b  = gtid >> 11;
    const int n0 = (gtid & 2047) * 4;
    float4 s = *(const float4*)(bias + n0);
#pragma unroll
    for (int p = 0; p < KSPLIT; ++p) {
        f16x4 v = *(const f16x4*)(part + p * (B_ * OUT_) + b * OUT_ + n0);
        s.x += (float)v[0]; s.y += (float)v[1];
        s.z += (float)v[2]; s.w += (float)v[3];
    }
    *(float4*)(out + b * OUT_ + n0) = s;
}

extern "C" void kernel_launch(void* const* d_in, const int* in_sizes, int n_in,
                              void* d_out, int out_size, void* d_ws, size_t ws_size,
                              hipStream_t stream) {
    const float*         x      = (const float*)d_in[0];
    const unsigned char* wp     = (const unsigned char*)d_in[1];
    const float*         scales = (const float*)d_in[2];
    const int*           zps    = (const int*)d_in[3];
    const float*         bias   = (const float*)d_in[4];
    float*               out    = (float*)d_out;

    char* ws = (char*)d_ws;
    uint4*          xfrag = (uint4*)ws;
    unsigned char*  wq    = (unsigned char*)(ws + OFF_WQ);
    uint4*          tab   = (uint4*)(ws + OFF_TAB);
    _Float16*       part  = (_Float16*)(ws + OFF_PART);
    int*            flag  = (int*)(ws + OFF_FLAG);

    k_flag<<<1, 256, 0, stream>>>((const unsigned*)wp, flag);
    k_wpack<<<512, 256, 0, stream>>>(wp, wq, flag);
    k_spack<<<4096, 256, 0, stream>>>(scales, zps, (uint2*)tab);
    k_pre<<<64, 256, 0, stream>>>(x, xfrag);
    k_main<<<512, 256, 0, stream>>>(xfrag, wq, tab, part);
    k_reduce<<<512, 256, 0, stream>>>(part, bias, out);
}

// Round 6
// 132.919 us; speedup vs baseline: 1.0901x; 1.0901x over previous
//
#include <hip/hip_runtime.h>
#include <hip/hip_bf16.h>

// out[64,8192] = x[64,8192] @ dequant(w2bit)[8192,8192]^T + bias
#define B_    64
#define IN_   8192
#define OUT_  8192
#define NG_   128      // quant groups per row (IN/64)
#define PB_   2048     // packed bytes per weight row (IN/4)
#define KSPLIT 16
#define KC    512      // k per k_main block

typedef float    f32x16 __attribute__((ext_vector_type(16)));
typedef short    s16x8  __attribute__((ext_vector_type(8)));
typedef _Float16 f16x4  __attribute__((ext_vector_type(4)));

// ws layout: xfrag 0..1MB | wq 1..17MB | sq 17..19MB | zflags 19MB | part 20..36MB
#define OFF_WQ   (1u << 20)
#define OFF_SQ   (17u << 20)
#define OFF_ZF   (19u << 20)
#define OFF_PART (20u << 20)

// ---------------- fused prep: role-split blocks ----------------
// 0..511  : weight transpose wp[row][16x128B] -> wq[kidx][row][128B] (LDS xpose)
//           per-block u8-vs-int32 self-detection from wp[0..1KB)
// 512..575: x fp32 -> bf16 in per-kidx 32x32-MFMA A-fragment slot order
// 576..639: scales fp32 -> bf16 sq[kidx][n][8 groups]; full zps==2 scan -> zflags
__global__ __launch_bounds__(256) void k_prep(
    const float* __restrict__ x, const unsigned char* __restrict__ wp,
    const float* __restrict__ scales, const int* __restrict__ zps,
    uint4* __restrict__ xfrag, unsigned char* __restrict__ wq,
    uint4* __restrict__ sq, int* __restrict__ zflags)
{
    __shared__ uint4 lds[2048];   // 32 KB (wpack role)
    __shared__ int zf;
    const int bid = blockIdx.x, tid = threadIdx.x;

    if (bid < 512) {
        // mode detect: int32-widened bytes are all <=255; raw u8 words are random
        const unsigned v = ((const unsigned*)wp)[tid];
        const bool u8mode = __any((int)(v > 255u));
        if (u8mode) {
            const uint4* src = (const uint4*)wp + bid * 2048;
#pragma unroll
            for (int i = 0; i < 8; ++i) lds[tid + i * 256] = src[tid + i * 256];
        } else {
            const int* src = (const int*)wp + bid * 32768;
#pragma unroll
            for (int i = 0; i < 8; ++i) {
                const int j = tid + i * 256;
                const int* p = src + j * 16;
                unsigned d[4];
#pragma unroll
                for (int w = 0; w < 4; ++w)
                    d[w] = (unsigned)(p[w*4] & 0xFF) | ((unsigned)(p[w*4+1] & 0xFF) << 8) |
                           ((unsigned)(p[w*4+2] & 0xFF) << 16) | ((unsigned)(p[w*4+3] & 0xFF) << 24);
                lds[j] = (uint4){d[0], d[1], d[2], d[3]};
            }
        }
        __syncthreads();
        const int c = tid >> 4, r = tid & 15;   // c = kidx, r = row-in-block
        uint4* dst = (uint4*)wq + ((unsigned)c * OUT_ + bid * 16 + r) * 8;
#pragma unroll
        for (int u = 0; u < 8; ++u) dst[u] = lds[r * 128 + c * 8 + u];
    } else if (bid < 576) {
        const int b2 = bid - 512;
        const int kidx = b2 >> 2, prt = b2 & 3;
#pragma unroll
        for (int i = 0; i < 4; ++i) {
            const int idx = prt * 1024 + i * 256 + tid;      // slot within kidx chunk
            const int sg = idx >> 6, lane = idx & 63;
            const int t = sg >> 1, mt = sg & 1;
            const int h = lane >> 5, m = lane & 31;
            const float* src = x + (mt * 32 + m) * IN_ + kidx * KC + h * 256 + t * 8;
            const float4 f0 = *(const float4*)src;
            const float4 f1 = *(const float4*)(src + 4);
            __hip_bfloat162 h0 = __float22bfloat162_rn(make_float2(f0.x, f0.y));
            __hip_bfloat162 h1 = __float22bfloat162_rn(make_float2(f0.z, f0.w));
            __hip_bfloat162 h2 = __float22bfloat162_rn(make_float2(f1.x, f1.y));
            __hip_bfloat162 h3 = __float22bfloat162_rn(make_float2(f1.z, f1.w));
            uint4 o;
            o.x = *(unsigned*)&h0; o.y = *(unsigned*)&h1;
            o.z = *(unsigned*)&h2; o.w = *(unsigned*)&h3;
            xfrag[kidx * 4096 + idx] = o;
        }
    } else {
        const int b3 = bid - 576;
        if (tid < 128) {
            const int n = b3 * 128 + tid;
#pragma unroll
            for (int kidx = 0; kidx < 16; ++kidx) {
                const float* sp = scales + n * NG_ + kidx * 8;
                const float4 s0 = *(const float4*)sp;
                const float4 s1 = *(const float4*)(sp + 4);
                __hip_bfloat162 h0 = __float22bfloat162_rn(make_float2(s0.x, s0.y));
                __hip_bfloat162 h1 = __float22bfloat162_rn(make_float2(s0.z, s0.w));
                __hip_bfloat162 h2 = __float22bfloat162_rn(make_float2(s1.x, s1.y));
                __hip_bfloat162 h3 = __float22bfloat162_rn(make_float2(s1.z, s1.w));
                uint4 o;
                o.x = *(unsigned*)&h0; o.y = *(unsigned*)&h1;
                o.z = *(unsigned*)&h2; o.w = *(unsigned*)&h3;
                sq[(unsigned)kidx * OUT_ + n] = o;
            }
        }
        if (tid == 0) zf = 0;
        __syncthreads();
        int bad = 0;
        const int4* zp4 = (const int4*)zps + b3 * 4096;
#pragma unroll
        for (int i = 0; i < 16; ++i) {
            const int4 z = zp4[i * 256 + tid];
            bad |= (z.x != 2) | (z.y != 2) | (z.z != 2) | (z.w != 2);
        }
        if (bad) zf = 1;
        __syncthreads();
        if (tid == 0) zflags[b3] = zf;
    }
}

// ---------------- main: 32 col-blocks(256) x 16 k-splits ----------------
// 256 thr = 4 waves; wave owns 64 cols = 2 col-groups of 32 (32x32x16 MFMA).
// K permutation (same on A and B, dot products invariant): MFMA step t,
// lane half h, elem j  <->  k = kidx*512 + h*256 + t*8 + j. Per-lane weight
// stream = 64 contiguous bytes; wave-load = 4 KB contiguous.
// Two-phase pipeline: load ph0 -> barrier -> issue ph1 loads -> compute ph0
// (ph1 in flight) -> barrier -> compute ph1.
__global__ __launch_bounds__(256, 2) void k_main(
    const uint4* __restrict__ xfrag, const unsigned char* __restrict__ wq,
    const uint2* __restrict__ sq2, const int* __restrict__ zflags,
    const int* __restrict__ zps, _Float16* __restrict__ part)
{
    __shared__ uint4 x_lds[4096];   // 2 x 32 KB phase buffers

    const int tid = threadIdx.x, wave = tid >> 6, lane = tid & 63;
    const int h = lane >> 5, n32 = lane & 31;
    const int kidx = blockIdx.x & (KSPLIT - 1);
    const int nblk = blockIdx.x >> 4;
    const int colbase = nblk * 256 + wave * 64;

    // ---- phase-0 loads ----
    uint4 w[2][4];
    uint2 sv[2];
    int ncol[2];
#pragma unroll
    for (int cg = 0; cg < 2; ++cg) {
        const int n = colbase + cg * 32 + n32;
        ncol[cg] = n;
        const uint4* wb = (const uint4*)(wq + ((unsigned)kidx * OUT_ + n) * 128 + h * 64);
        w[cg][0] = wb[0];
        w[cg][1] = wb[1];
        sv[cg] = sq2[((unsigned)kidx * OUT_ + n) * 2 + h];
    }
    const int zv = zflags[lane & 63];
#pragma unroll
    for (int i = 0; i < 8; ++i) {
        const int sg = wave * 8 + i;
        const uint4* src = xfrag + kidx * 4096 + sg * 64 + lane;
        __builtin_amdgcn_global_load_lds(
            (const __attribute__((address_space(1))) unsigned*)src,
            (__attribute__((address_space(3))) unsigned*)((char*)x_lds + sg * 1024),
            16, 0, 0);
    }
    const bool zgen = __any(zv != 0);
    __syncthreads();   // drain phase-0 only

    // ---- issue phase-1 loads (fly during phase-0 compute) ----
#pragma unroll
    for (int cg = 0; cg < 2; ++cg) {
        const uint4* wb = (const uint4*)(wq + ((unsigned)kidx * OUT_ + ncol[cg]) * 128 + h * 64);
        w[cg][2] = wb[2];
        w[cg][3] = wb[3];
    }
#pragma unroll
    for (int i = 0; i < 8; ++i) {
        const int sg = 32 + wave * 8 + i;
        const uint4* src = xfrag + kidx * 4096 + sg * 64 + lane;
        __builtin_amdgcn_global_load_lds(
            (const __attribute__((address_space(1))) unsigned*)src,
            (__attribute__((address_space(3))) unsigned*)((char*)x_lds + sg * 1024),
            16, 0, 0);
    }

    // ---- dequant LUTs: {(c-zp)*s, c=0..3} bf16; tl={v0,v1}, th={v2,v3} ----
    unsigned tl[2][4], th[2][4];
#pragma unroll
    for (int cg = 0; cg < 2; ++cg) {
#pragma unroll
        for (int gg = 0; gg < 4; ++gg) {
            const unsigned dwv = (gg >> 1) ? sv[cg].y : sv[cg].x;
            const unsigned s16 = (gg & 1) ? (dwv >> 16) : (dwv & 0xFFFFu);
            if (!zgen) {   // zp==2: v={-2s,-s,0,s}; -2s via bf16 exponent+1
                const unsigned m1 = s16 | 0x8000u;
                const unsigned m2 = (s16 + 0x0080u) | 0x8000u;
                tl[cg][gg] = m2 | (m1 << 16);
                th[cg][gg] = s16 << 16;
            } else {       // general zp (correct, rare)
                union { unsigned u; float f; } sf; sf.u = s16 << 16;
                const int g = kidx * 8 + h * 4 + gg;
                const float zf = (float)zps[ncol[cg] * NG_ + g];
                const float v0 = (0.f - zf) * sf.f, v1 = (1.f - zf) * sf.f;
                const float v2 = (2.f - zf) * sf.f, v3 = (3.f - zf) * sf.f;
                __hip_bfloat162 lo = __float22bfloat162_rn(make_float2(v0, v1));
                __hip_bfloat162 hi = __float22bfloat162_rn(make_float2(v2, v3));
                tl[cg][gg] = *(unsigned*)&lo;
                th[cg][gg] = *(unsigned*)&hi;
            }
        }
    }

    f32x16 acc[2][2];
#pragma unroll
    for (int cg = 0; cg < 2; ++cg)
#pragma unroll
        for (int mt = 0; mt < 2; ++mt)
#pragma unroll
            for (int r = 0; r < 16; ++r) acc[cg][mt][r] = 0.f;

    // ---- compute: 2 phases x 16 MFMA steps ----
#pragma unroll
    for (int p = 0; p < 2; ++p) {
        if (p) __syncthreads();   // drain phase-1 loads (issued ~one phase ago)
#pragma unroll
        for (int t8 = 0; t8 < 2; ++t8) {
#pragma unroll
            for (int dw = 0; dw < 4; ++dw) {
#pragma unroll
                for (int hf = 0; hf < 2; ++hf) {
                    const int t = p * 16 + t8 * 8 + dw * 2 + hf;
                    union { uint4 u4; s16x8 s8; } av[2];
#pragma unroll
                    for (int mt = 0; mt < 2; ++mt)
                        av[mt].u4 = x_lds[(t * 2 + mt) * 64 + lane];
#pragma unroll
                    for (int cg = 0; cg < 2; ++cg) {
                        const uint4 wc = w[cg][p * 2 + t8];
                        const unsigned wdw = ((const unsigned*)&wc)[dw];
                        const unsigned u = hf ? (wdw >> 16) : (wdw & 0xFFFFu);
                        const unsigned tlv = tl[cg][p * 2 + t8];
                        const unsigned thv = th[cg][p * 2 + t8];
                        union { unsigned w_[4]; s16x8 s8; } bf;
#pragma unroll
                        for (int m = 0; m < 4; ++m) {
                            const unsigned c0 = (u >> (4 * m)) & 3u;
                            const unsigned c1 = (u >> (4 * m + 2)) & 3u;
                            const unsigned sel = 0x01000100u + c0 * 0x0202u + c1 * 0x02020000u;
                            bf.w_[m] = __builtin_amdgcn_perm(thv, tlv, sel);
                        }
#pragma unroll
                        for (int mt = 0; mt < 2; ++mt)
                            acc[cg][mt] = __builtin_amdgcn_mfma_f32_32x32x16_bf16(
                                av[mt].s8, bf.s8, acc[cg][mt], 0, 0, 0);
                    }
                }
            }
        }
    }

    // ---- epilogue: 32x32 C/D layout col=lane&31, row=(r&3)+8*(r>>2)+4*h ----
    _Float16* pp = part + kidx * (B_ * OUT_);
#pragma unroll
    for (int cg = 0; cg < 2; ++cg) {
        const int col = ncol[cg];
#pragma unroll
        for (int mt = 0; mt < 2; ++mt)
#pragma unroll
            for (int r = 0; r < 16; ++r) {
                const int row = (r & 3) + 8 * (r >> 2) + 4 * h;
                pp[(mt * 32 + row) * OUT_ + col] = (_Float16)acc[cg][mt][r];
            }
    }
}

// ---------------- reduce: out = bias + sum of 16 fp16 partial planes ----------------
__global__ __launch_bounds__(256) void k_reduce(const _Float16* __restrict__ part,
                                                const float* __restrict__ bias,
                                                float* __restrict__ out) {
    const int gtid = blockIdx.x * 256 + threadIdx.x;
    const int b  = gtid >> 11;
    const int n0 = (gtid & 2047) * 4;
    float4 s = *(const float4*)(bias + n0);
#pragma unroll
    for (int p = 0; p < KSPLIT; ++p) {
        const f16x4 v = *(const f16x4*)(part + p * (B_ * OUT_) + b * OUT_ + n0);
        s.x += (float)v[0]; s.y += (float)v[1];
        s.z += (float)v[2]; s.w += (float)v[3];
    }
    *(float4*)(out + b * OUT_ + n0) = s;
}

extern "C" void kernel_launch(void* const* d_in, const int* in_sizes, int n_in,
                              void* d_out, int out_size, void* d_ws, size_t ws_size,
                              hipStream_t stream) {
    const float*         x      = (const float*)d_in[0];
    const unsigned char* wp     = (const unsigned char*)d_in[1];
    const float*         scales = (const float*)d_in[2];
    const int*           zps    = (const int*)d_in[3];
    const float*         bias   = (const float*)d_in[4];
    float*               out    = (float*)d_out;

    char* ws = (char*)d_ws;
    uint4*         xfrag = (uint4*)ws;
    unsigned char* wq    = (unsigned char*)(ws + OFF_WQ);
    uint4*         sq    = (uint4*)(ws + OFF_SQ);
    int*           zfl   = (int*)(ws + OFF_ZF);
    _Float16*      part  = (_Float16*)(ws + OFF_PART);

    k_prep<<<640, 256, 0, stream>>>(x, wp, scales, zps, xfrag, wq, sq, zfl);
    k_main<<<512, 256, 0, stream>>>(xfrag, wq, (const uint2*)sq, zfl, zps, part);
    k_reduce<<<512, 256, 0, stream>>>(part, bias, out);
}